// Round 1
// baseline (4381.671 us; speedup 1.0000x reference)
//
#include <hip/hip_runtime.h>

#define N_NODES 100000
#define N_EDGES 1600000
#define IN_DIM 256
#define HIDDEN 128
#define OUT_DIM 64

// ---------------------------------------------------------------------------
// degree count: deg[dst[e]] += 1  (deg buffer pre-zeroed via hipMemsetAsync)
// ---------------------------------------------------------------------------
__global__ void k_deg(const int* __restrict__ dst, float* __restrict__ deg) {
    int e = blockIdx.x * blockDim.x + threadIdx.x;
    if (e < N_EDGES) atomicAdd(&deg[dst[e]], 1.0f);
}

// dinv[i] = rsqrt(deg[i] + 1)   (in place on the deg buffer)
__global__ void k_dinv(float* __restrict__ deg) {
    int i = blockIdx.x * blockDim.x + threadIdx.x;
    if (i < N_NODES) deg[i] = rsqrtf(deg[i] + 1.0f);
}

// ---------------------------------------------------------------------------
// GEMM1: H[M][128] = X[M][256] @ W1[256][128]
// epilogue also writes AGG[i][c] = H[i][c] * dinv[i]^2   (self-loop init)
// tile: 64 rows x 128 cols, K-chunks of 64; thread micro-tile 4 rows x (4+4) cols
// ---------------------------------------------------------------------------
__launch_bounds__(256)
__global__ void k_gemm1(const float* __restrict__ A, const float* __restrict__ B,
                        const float* __restrict__ dinv,
                        float* __restrict__ H, float* __restrict__ AGG) {
    __shared__ __attribute__((aligned(16))) float As[64 * 68];   // ld 68
    __shared__ __attribute__((aligned(16))) float Bs[64 * 132];  // ld 132

    const int t = threadIdx.x;
    const int row0 = blockIdx.x * 64;
    const int tcol = t & 15;      // 16 col-groups
    const int trow = t >> 4;      // 16 row-groups of 4 rows
    const int trow4 = trow * 4;
    const int c0 = tcol * 4;

    float acc[4][8];
    #pragma unroll
    for (int r = 0; r < 4; ++r)
        #pragma unroll
        for (int c = 0; c < 8; ++c) acc[r][c] = 0.f;

    for (int k0 = 0; k0 < IN_DIM; k0 += 64) {
        // stage A tile (64 rows x 64 k), coalesced float4
        #pragma unroll
        for (int p = 0; p < 4; ++p) {
            int lin = p * 1024 + t * 4;
            int r = lin >> 6;
            int kk = lin & 63;
            int grow = row0 + r;
            float4 v = make_float4(0.f, 0.f, 0.f, 0.f);
            if (grow < N_NODES) v = *(const float4*)&A[grow * IN_DIM + k0 + kk];
            *(float4*)&As[r * 68 + kk] = v;
        }
        // stage B tile (64 k x 128 cols)
        #pragma unroll
        for (int p = 0; p < 8; ++p) {
            int lin = p * 1024 + t * 4;
            int kk = lin >> 7;
            int c = lin & 127;
            float4 v = *(const float4*)&B[(k0 + kk) * HIDDEN + c];
            *(float4*)&Bs[kk * 132 + c] = v;
        }
        __syncthreads();

        #pragma unroll 8
        for (int kk = 0; kk < 64; ++kk) {
            float a[4];
            #pragma unroll
            for (int r = 0; r < 4; ++r) a[r] = As[(trow4 + r) * 68 + kk];
            const float4 b0 = *(const float4*)&Bs[kk * 132 + c0];
            const float4 b1 = *(const float4*)&Bs[kk * 132 + 64 + c0];
            #pragma unroll
            for (int r = 0; r < 4; ++r) {
                acc[r][0] = fmaf(a[r], b0.x, acc[r][0]);
                acc[r][1] = fmaf(a[r], b0.y, acc[r][1]);
                acc[r][2] = fmaf(a[r], b0.z, acc[r][2]);
                acc[r][3] = fmaf(a[r], b0.w, acc[r][3]);
                acc[r][4] = fmaf(a[r], b1.x, acc[r][4]);
                acc[r][5] = fmaf(a[r], b1.y, acc[r][5]);
                acc[r][6] = fmaf(a[r], b1.z, acc[r][6]);
                acc[r][7] = fmaf(a[r], b1.w, acc[r][7]);
            }
        }
        __syncthreads();
    }

    #pragma unroll
    for (int r = 0; r < 4; ++r) {
        int grow = row0 + trow4 + r;
        if (grow < N_NODES) {
            float s = dinv[grow];
            s = s * s;
            float4 v0 = make_float4(acc[r][0], acc[r][1], acc[r][2], acc[r][3]);
            float4 v1 = make_float4(acc[r][4], acc[r][5], acc[r][6], acc[r][7]);
            *(float4*)&H[grow * HIDDEN + c0] = v0;
            *(float4*)&H[grow * HIDDEN + 64 + c0] = v1;
            *(float4*)&AGG[grow * HIDDEN + c0] =
                make_float4(v0.x * s, v0.y * s, v0.z * s, v0.w * s);
            *(float4*)&AGG[grow * HIDDEN + 64 + c0] =
                make_float4(v1.x * s, v1.y * s, v1.z * s, v1.w * s);
        }
    }
}

// ---------------------------------------------------------------------------
// scatter layer1: AGG[dst] += H[src] * dinv[src]*dinv[dst]
// 32 lanes per edge (float4 each over 128 cols)
// ---------------------------------------------------------------------------
__global__ void k_scatter1(const int* __restrict__ src, const int* __restrict__ dst,
                           const float* __restrict__ dinv,
                           const float* __restrict__ H, float* __restrict__ AGG) {
    int tid = blockIdx.x * blockDim.x + threadIdx.x;
    int e = tid >> 5;
    if (e >= N_EDGES) return;
    int j = (tid & 31) * 4;
    int s = src[e], d = dst[e];
    float coef = dinv[s] * dinv[d];
    float4 v = *(const float4*)&H[s * HIDDEN + j];
    float* out = &AGG[d * HIDDEN + j];
    atomicAdd(out + 0, v.x * coef);
    atomicAdd(out + 1, v.y * coef);
    atomicAdd(out + 2, v.z * coef);
    atomicAdd(out + 3, v.w * coef);
}

// ---------------------------------------------------------------------------
// GEMM2: H2[M][64] = relu(AGG[M][128] + b1) @ W2[128][64]
// epilogue writes H2 and OUT init = H2 * dinv^2
// ---------------------------------------------------------------------------
__launch_bounds__(256)
__global__ void k_gemm2(const float* __restrict__ A, const float* __restrict__ B,
                        const float* __restrict__ bias1,
                        const float* __restrict__ dinv,
                        float* __restrict__ H2, float* __restrict__ OUTI) {
    __shared__ __attribute__((aligned(16))) float As[64 * 68];
    __shared__ __attribute__((aligned(16))) float Bs[64 * 68];

    const int t = threadIdx.x;
    const int row0 = blockIdx.x * 64;
    const int tcol = t & 15;
    const int trow = t >> 4;
    const int trow4 = trow * 4;
    const int c0 = tcol * 4;

    float acc[4][4];
    #pragma unroll
    for (int r = 0; r < 4; ++r)
        #pragma unroll
        for (int c = 0; c < 4; ++c) acc[r][c] = 0.f;

    for (int k0 = 0; k0 < HIDDEN; k0 += 64) {
        // stage A tile with fused bias+relu
        #pragma unroll
        for (int p = 0; p < 4; ++p) {
            int lin = p * 1024 + t * 4;
            int r = lin >> 6;
            int kk = lin & 63;
            int grow = row0 + r;
            float4 v = make_float4(0.f, 0.f, 0.f, 0.f);
            if (grow < N_NODES) v = *(const float4*)&A[grow * HIDDEN + k0 + kk];
            float4 bb = *(const float4*)&bias1[k0 + kk];
            v.x = fmaxf(v.x + bb.x, 0.f);
            v.y = fmaxf(v.y + bb.y, 0.f);
            v.z = fmaxf(v.z + bb.z, 0.f);
            v.w = fmaxf(v.w + bb.w, 0.f);
            *(float4*)&As[r * 68 + kk] = v;
        }
        // stage B tile (64 k x 64 cols)
        #pragma unroll
        for (int p = 0; p < 4; ++p) {
            int lin = p * 1024 + t * 4;
            int kk = lin >> 6;
            int c = lin & 63;
            float4 v = *(const float4*)&B[(k0 + kk) * OUT_DIM + c];
            *(float4*)&Bs[kk * 68 + c] = v;
        }
        __syncthreads();

        #pragma unroll 8
        for (int kk = 0; kk < 64; ++kk) {
            float a[4];
            #pragma unroll
            for (int r = 0; r < 4; ++r) a[r] = As[(trow4 + r) * 68 + kk];
            const float4 b0 = *(const float4*)&Bs[kk * 68 + c0];
            #pragma unroll
            for (int r = 0; r < 4; ++r) {
                acc[r][0] = fmaf(a[r], b0.x, acc[r][0]);
                acc[r][1] = fmaf(a[r], b0.y, acc[r][1]);
                acc[r][2] = fmaf(a[r], b0.z, acc[r][2]);
                acc[r][3] = fmaf(a[r], b0.w, acc[r][3]);
            }
        }
        __syncthreads();
    }

    #pragma unroll
    for (int r = 0; r < 4; ++r) {
        int grow = row0 + trow4 + r;
        if (grow < N_NODES) {
            float s = dinv[grow];
            s = s * s;
            float4 v0 = make_float4(acc[r][0], acc[r][1], acc[r][2], acc[r][3]);
            *(float4*)&H2[grow * OUT_DIM + c0] = v0;
            *(float4*)&OUTI[grow * OUT_DIM + c0] =
                make_float4(v0.x * s, v0.y * s, v0.z * s, v0.w * s);
        }
    }
}

// ---------------------------------------------------------------------------
// scatter layer2: OUT[dst] += H2[src] * coef   (16 lanes per edge)
// ---------------------------------------------------------------------------
__global__ void k_scatter2(const int* __restrict__ src, const int* __restrict__ dst,
                           const float* __restrict__ dinv,
                           const float* __restrict__ H2, float* __restrict__ OUT) {
    int tid = blockIdx.x * blockDim.x + threadIdx.x;
    int e = tid >> 4;
    if (e >= N_EDGES) return;
    int j = (tid & 15) * 4;
    int s = src[e], d = dst[e];
    float coef = dinv[s] * dinv[d];
    float4 v = *(const float4*)&H2[s * OUT_DIM + j];
    float* out = &OUT[d * OUT_DIM + j];
    atomicAdd(out + 0, v.x * coef);
    atomicAdd(out + 1, v.y * coef);
    atomicAdd(out + 2, v.z * coef);
    atomicAdd(out + 3, v.w * coef);
}

// final: OUT = relu(OUT + b2)
__global__ void k_finish(float* __restrict__ Y, const float* __restrict__ b2) {
    int i = blockIdx.x * blockDim.x + threadIdx.x;
    if (i < N_NODES * (OUT_DIM / 4)) {
        int c = (i & 15) * 4;
        float4 v = *(float4*)&Y[i * 4];
        float4 bb = *(const float4*)&b2[c];
        v.x = fmaxf(v.x + bb.x, 0.f);
        v.y = fmaxf(v.y + bb.y, 0.f);
        v.z = fmaxf(v.z + bb.z, 0.f);
        v.w = fmaxf(v.w + bb.w, 0.f);
        *(float4*)&Y[i * 4] = v;
    }
}

extern "C" void kernel_launch(void* const* d_in, const int* in_sizes, int n_in,
                              void* d_out, int out_size, void* d_ws, size_t ws_size,
                              hipStream_t stream) {
    const float* x  = (const float*)d_in[0];
    const int* ei   = (const int*)d_in[1];     // [2][E]: src then dst
    const float* W1 = (const float*)d_in[2];
    const float* b1 = (const float*)d_in[3];
    const float* W2 = (const float*)d_in[4];
    const float* b2 = (const float*)d_in[5];
    float* out = (float*)d_out;

    const int* src = ei;
    const int* dst = ei + N_EDGES;

    char* ws = (char*)d_ws;
    float* dinv = (float*)ws;                              // 400 KB (deg then dinv)
    float* h1   = (float*)(ws + 524288);                   // 51.2 MB (h1, reused as h2)
    float* agg1 = (float*)(ws + 524288 + 51200000);        // 51.2 MB
    float* h2   = h1;

    hipMemsetAsync(dinv, 0, N_NODES * sizeof(float), stream);
    k_deg<<<(N_EDGES + 255) / 256, 256, 0, stream>>>(dst, dinv);
    k_dinv<<<(N_NODES + 255) / 256, 256, 0, stream>>>(dinv);

    // layer 1
    k_gemm1<<<(N_NODES + 63) / 64, 256, 0, stream>>>(x, W1, dinv, h1, agg1);
    k_scatter1<<<(N_EDGES * 32 + 255) / 256, 256, 0, stream>>>(src, dst, dinv, h1, agg1);

    // layer 2 (bias1+relu fused into A-load of GEMM2)
    k_gemm2<<<(N_NODES + 63) / 64, 256, 0, stream>>>(agg1, W2, b1, dinv, h2, out);
    k_scatter2<<<(N_EDGES * 16 + 255) / 256, 256, 0, stream>>>(src, dst, dinv, h2, out);
    k_finish<<<(N_NODES * 16 + 255) / 256, 256, 0, stream>>>(out, b2);
}

// Round 2
// 640.885 us; speedup vs baseline: 6.8369x; 6.8369x over previous
//
#include <hip/hip_runtime.h>

#define N_NODES 100000
#define N_EDGES 1600000
#define IN_DIM 256
#define HIDDEN 128
#define OUT_DIM 64
#define NBLK_SCAN 391  // ceil(100000/256)

// ---------------------------------------------------------------------------
// degree count (int): deg[dst[e]] += 1   (deg pre-zeroed)
// ---------------------------------------------------------------------------
__global__ void k_deg(const int* __restrict__ dst, int* __restrict__ deg) {
    int e = blockIdx.x * blockDim.x + threadIdx.x;
    if (e < N_EDGES) atomicAdd(&deg[dst[e]], 1);
}

// dinv[i] = rsqrt(deg[i] + 1)
__global__ void k_dinv(const int* __restrict__ deg, float* __restrict__ dinv) {
    int i = blockIdx.x * blockDim.x + threadIdx.x;
    if (i < N_NODES) dinv[i] = rsqrtf((float)deg[i] + 1.0f);
}

// ---------------------------------------------------------------------------
// 3-kernel exclusive scan of deg -> rowstart
// ---------------------------------------------------------------------------
__global__ void k_scan1(const int* __restrict__ deg, int* __restrict__ rowstart,
                        int* __restrict__ bsum) {
    __shared__ int tmp[256];
    int t = threadIdx.x;
    int i = blockIdx.x * 256 + t;
    int v = (i < N_NODES) ? deg[i] : 0;
    tmp[t] = v;
    __syncthreads();
    #pragma unroll
    for (int off = 1; off < 256; off <<= 1) {
        int p = (t >= off) ? tmp[t - off] : 0;
        __syncthreads();
        tmp[t] += p;
        __syncthreads();
    }
    if (i < N_NODES) rowstart[i] = tmp[t] - v;  // exclusive
    if (t == 255) bsum[blockIdx.x] = tmp[255];
}

__global__ void k_scan2(int* __restrict__ bsum, int* __restrict__ rowstart) {
    __shared__ int tmp[512];
    int t = threadIdx.x;
    int v = (t < NBLK_SCAN) ? bsum[t] : 0;
    tmp[t] = v;
    __syncthreads();
    #pragma unroll
    for (int off = 1; off < 512; off <<= 1) {
        int p = (t >= off) ? tmp[t - off] : 0;
        __syncthreads();
        tmp[t] += p;
        __syncthreads();
    }
    if (t < NBLK_SCAN) bsum[t] = tmp[t] - v;  // exclusive block offsets
    if (t == 0) rowstart[N_NODES] = N_EDGES;
}

__global__ void k_scan3(int* __restrict__ rowstart, const int* __restrict__ bsum) {
    int i = blockIdx.x * 256 + threadIdx.x;
    if (i < N_NODES) rowstart[i] += bsum[blockIdx.x];
}

// ---------------------------------------------------------------------------
// bucket edges by dst: esrc[p]=src, ecoef[p]=dinv[src]*dinv[dst]
// (cnt pre-zeroed; order within a bucket nondeterministic — f32 ulp only)
// ---------------------------------------------------------------------------
__global__ void k_bucket(const int* __restrict__ src, const int* __restrict__ dst,
                         const float* __restrict__ dinv,
                         const int* __restrict__ rowstart, int* __restrict__ cnt,
                         int* __restrict__ esrc, float* __restrict__ ecoef) {
    int e = blockIdx.x * blockDim.x + threadIdx.x;
    if (e >= N_EDGES) return;
    int s = src[e], d = dst[e];
    int p = rowstart[d] + atomicAdd(&cnt[d], 1);
    esrc[p] = s;
    ecoef[p] = dinv[s] * dinv[d];
}

// ---------------------------------------------------------------------------
// GEMM1: H[M][128] = X[M][256] @ W1[256][128]
// ---------------------------------------------------------------------------
__launch_bounds__(256)
__global__ void k_gemm1(const float* __restrict__ A, const float* __restrict__ B,
                        float* __restrict__ H) {
    __shared__ __attribute__((aligned(16))) float As[64 * 68];
    __shared__ __attribute__((aligned(16))) float Bs[64 * 132];

    const int t = threadIdx.x;
    const int row0 = blockIdx.x * 64;
    const int tcol = t & 15;
    const int trow4 = (t >> 4) * 4;
    const int c0 = tcol * 4;

    float acc[4][8];
    #pragma unroll
    for (int r = 0; r < 4; ++r)
        #pragma unroll
        for (int c = 0; c < 8; ++c) acc[r][c] = 0.f;

    for (int k0 = 0; k0 < IN_DIM; k0 += 64) {
        #pragma unroll
        for (int p = 0; p < 4; ++p) {
            int lin = p * 1024 + t * 4;
            int r = lin >> 6;
            int kk = lin & 63;
            int grow = row0 + r;
            float4 v = make_float4(0.f, 0.f, 0.f, 0.f);
            if (grow < N_NODES) v = *(const float4*)&A[grow * IN_DIM + k0 + kk];
            *(float4*)&As[r * 68 + kk] = v;
        }
        #pragma unroll
        for (int p = 0; p < 8; ++p) {
            int lin = p * 1024 + t * 4;
            int kk = lin >> 7;
            int c = lin & 127;
            float4 v = *(const float4*)&B[(k0 + kk) * HIDDEN + c];
            *(float4*)&Bs[kk * 132 + c] = v;
        }
        __syncthreads();

        #pragma unroll 8
        for (int kk = 0; kk < 64; ++kk) {
            float a[4];
            #pragma unroll
            for (int r = 0; r < 4; ++r) a[r] = As[(trow4 + r) * 68 + kk];
            const float4 b0 = *(const float4*)&Bs[kk * 132 + c0];
            const float4 b1 = *(const float4*)&Bs[kk * 132 + 64 + c0];
            #pragma unroll
            for (int r = 0; r < 4; ++r) {
                acc[r][0] = fmaf(a[r], b0.x, acc[r][0]);
                acc[r][1] = fmaf(a[r], b0.y, acc[r][1]);
                acc[r][2] = fmaf(a[r], b0.z, acc[r][2]);
                acc[r][3] = fmaf(a[r], b0.w, acc[r][3]);
                acc[r][4] = fmaf(a[r], b1.x, acc[r][4]);
                acc[r][5] = fmaf(a[r], b1.y, acc[r][5]);
                acc[r][6] = fmaf(a[r], b1.z, acc[r][6]);
                acc[r][7] = fmaf(a[r], b1.w, acc[r][7]);
            }
        }
        __syncthreads();
    }

    #pragma unroll
    for (int r = 0; r < 4; ++r) {
        int grow = row0 + trow4 + r;
        if (grow < N_NODES) {
            *(float4*)&H[grow * HIDDEN + c0] =
                make_float4(acc[r][0], acc[r][1], acc[r][2], acc[r][3]);
            *(float4*)&H[grow * HIDDEN + 64 + c0] =
                make_float4(acc[r][4], acc[r][5], acc[r][6], acc[r][7]);
        }
    }
}

// ---------------------------------------------------------------------------
// gather layer1: AGG[n] = relu( sum_e coef*H[src] + dinv[n]^2*H[n] + b1 )
// 32 lanes per node (128 cols), 8 nodes per block
// ---------------------------------------------------------------------------
__launch_bounds__(256)
__global__ void k_gather1(const int* __restrict__ rowstart, const int* __restrict__ esrc,
                          const float* __restrict__ ecoef, const float* __restrict__ dinv,
                          const float* __restrict__ H, const float* __restrict__ b1,
                          float* __restrict__ AGG) {
    int n = blockIdx.x * 8 + (threadIdx.x >> 5);
    if (n >= N_NODES) return;
    int j = (threadIdx.x & 31) * 4;

    float s = dinv[n];
    s = s * s;
    float4 h = *(const float4*)&H[n * HIDDEN + j];
    float4 acc = make_float4(h.x * s, h.y * s, h.z * s, h.w * s);

    int p0 = rowstart[n], p1 = rowstart[n + 1];
    for (int p = p0; p < p1; ++p) {
        int sidx = esrc[p];
        float c = ecoef[p];
        float4 v = *(const float4*)&H[sidx * HIDDEN + j];
        acc.x = fmaf(v.x, c, acc.x);
        acc.y = fmaf(v.y, c, acc.y);
        acc.z = fmaf(v.z, c, acc.z);
        acc.w = fmaf(v.w, c, acc.w);
    }
    float4 bb = *(const float4*)&b1[j];
    acc.x = fmaxf(acc.x + bb.x, 0.f);
    acc.y = fmaxf(acc.y + bb.y, 0.f);
    acc.z = fmaxf(acc.z + bb.z, 0.f);
    acc.w = fmaxf(acc.w + bb.w, 0.f);
    *(float4*)&AGG[n * HIDDEN + j] = acc;
}

// ---------------------------------------------------------------------------
// GEMM2: H2[M][64] = AGG[M][128] @ W2[128][64]   (AGG already relu'd+biased)
// ---------------------------------------------------------------------------
__launch_bounds__(256)
__global__ void k_gemm2(const float* __restrict__ A, const float* __restrict__ B,
                        float* __restrict__ H2) {
    __shared__ __attribute__((aligned(16))) float As[64 * 68];
    __shared__ __attribute__((aligned(16))) float Bs[64 * 68];

    const int t = threadIdx.x;
    const int row0 = blockIdx.x * 64;
    const int tcol = t & 15;
    const int trow4 = (t >> 4) * 4;
    const int c0 = tcol * 4;

    float acc[4][4];
    #pragma unroll
    for (int r = 0; r < 4; ++r)
        #pragma unroll
        for (int c = 0; c < 4; ++c) acc[r][c] = 0.f;

    for (int k0 = 0; k0 < HIDDEN; k0 += 64) {
        #pragma unroll
        for (int p = 0; p < 4; ++p) {
            int lin = p * 1024 + t * 4;
            int r = lin >> 6;
            int kk = lin & 63;
            int grow = row0 + r;
            float4 v = make_float4(0.f, 0.f, 0.f, 0.f);
            if (grow < N_NODES) v = *(const float4*)&A[grow * HIDDEN + k0 + kk];
            *(float4*)&As[r * 68 + kk] = v;
        }
        #pragma unroll
        for (int p = 0; p < 4; ++p) {
            int lin = p * 1024 + t * 4;
            int kk = lin >> 6;
            int c = lin & 63;
            float4 v = *(const float4*)&B[(k0 + kk) * OUT_DIM + c];
            *(float4*)&Bs[kk * 68 + c] = v;
        }
        __syncthreads();

        #pragma unroll 8
        for (int kk = 0; kk < 64; ++kk) {
            float a[4];
            #pragma unroll
            for (int r = 0; r < 4; ++r) a[r] = As[(trow4 + r) * 68 + kk];
            const float4 b0 = *(const float4*)&Bs[kk * 68 + c0];
            #pragma unroll
            for (int r = 0; r < 4; ++r) {
                acc[r][0] = fmaf(a[r], b0.x, acc[r][0]);
                acc[r][1] = fmaf(a[r], b0.y, acc[r][1]);
                acc[r][2] = fmaf(a[r], b0.z, acc[r][2]);
                acc[r][3] = fmaf(a[r], b0.w, acc[r][3]);
            }
        }
        __syncthreads();
    }

    #pragma unroll
    for (int r = 0; r < 4; ++r) {
        int grow = row0 + trow4 + r;
        if (grow < N_NODES)
            *(float4*)&H2[grow * OUT_DIM + c0] =
                make_float4(acc[r][0], acc[r][1], acc[r][2], acc[r][3]);
    }
}

// ---------------------------------------------------------------------------
// gather layer2: OUT[n] = relu( sum coef*H2[src] + dinv^2*H2[n] + b2 )
// 16 lanes per node (64 cols), 16 nodes per block
// ---------------------------------------------------------------------------
__launch_bounds__(256)
__global__ void k_gather2(const int* __restrict__ rowstart, const int* __restrict__ esrc,
                          const float* __restrict__ ecoef, const float* __restrict__ dinv,
                          const float* __restrict__ H2, const float* __restrict__ b2,
                          float* __restrict__ OUT) {
    int n = blockIdx.x * 16 + (threadIdx.x >> 4);
    if (n >= N_NODES) return;
    int j = (threadIdx.x & 15) * 4;

    float s = dinv[n];
    s = s * s;
    float4 h = *(const float4*)&H2[n * OUT_DIM + j];
    float4 acc = make_float4(h.x * s, h.y * s, h.z * s, h.w * s);

    int p0 = rowstart[n], p1 = rowstart[n + 1];
    for (int p = p0; p < p1; ++p) {
        int sidx = esrc[p];
        float c = ecoef[p];
        float4 v = *(const float4*)&H2[sidx * OUT_DIM + j];
        acc.x = fmaf(v.x, c, acc.x);
        acc.y = fmaf(v.y, c, acc.y);
        acc.z = fmaf(v.z, c, acc.z);
        acc.w = fmaf(v.w, c, acc.w);
    }
    float4 bb = *(const float4*)&b2[j];
    acc.x = fmaxf(acc.x + bb.x, 0.f);
    acc.y = fmaxf(acc.y + bb.y, 0.f);
    acc.z = fmaxf(acc.z + bb.z, 0.f);
    acc.w = fmaxf(acc.w + bb.w, 0.f);
    *(float4*)&OUT[n * OUT_DIM + j] = acc;
}

extern "C" void kernel_launch(void* const* d_in, const int* in_sizes, int n_in,
                              void* d_out, int out_size, void* d_ws, size_t ws_size,
                              hipStream_t stream) {
    const float* x  = (const float*)d_in[0];
    const int* ei   = (const int*)d_in[1];
    const float* W1 = (const float*)d_in[2];
    const float* b1 = (const float*)d_in[3];
    const float* W2 = (const float*)d_in[4];
    const float* b2 = (const float*)d_in[5];
    float* out = (float*)d_out;

    const int* src = ei;
    const int* dst = ei + N_EDGES;

    char* ws = (char*)d_ws;
    int*   deg      = (int*)  (ws + 0x000000);   // 400,000 B
    float* dinv     = (float*)(ws + 0x080000);   // 400,000 B
    int*   rowstart = (int*)  (ws + 0x100000);   // 400,004 B
    int*   cnt      = (int*)  (ws + 0x180000);   // 400,000 B
    int*   bsum     = (int*)  (ws + 0x200000);   // 1,564 B
    int*   esrc     = (int*)  (ws + 0x280000);   // 6.4 MB
    float* ecoef    = (float*)(ws + 0x8C0000);   // 6.4 MB
    float* h1       = (float*)(ws + 0x1000000);  // 51.2 MB
    float* agg1     = (float*)(ws + 0x4400000);  // 51.2 MB
    float* h2       = h1;                        // h1 dead after gather1

    hipMemsetAsync(deg, 0, N_NODES * sizeof(int), stream);
    hipMemsetAsync(cnt, 0, N_NODES * sizeof(int), stream);

    // CSR build
    k_deg<<<(N_EDGES + 255) / 256, 256, 0, stream>>>(dst, deg);
    k_dinv<<<(N_NODES + 255) / 256, 256, 0, stream>>>(deg, dinv);
    k_scan1<<<NBLK_SCAN, 256, 0, stream>>>(deg, rowstart, bsum);
    k_scan2<<<1, 512, 0, stream>>>(bsum, rowstart);
    k_scan3<<<NBLK_SCAN, 256, 0, stream>>>(rowstart, bsum);
    k_bucket<<<(N_EDGES + 255) / 256, 256, 0, stream>>>(src, dst, dinv, rowstart,
                                                        cnt, esrc, ecoef);

    // layer 1
    k_gemm1<<<(N_NODES + 63) / 64, 256, 0, stream>>>(x, W1, h1);
    k_gather1<<<(N_NODES + 7) / 8, 256, 0, stream>>>(rowstart, esrc, ecoef, dinv,
                                                     h1, b1, agg1);
    // layer 2
    k_gemm2<<<(N_NODES + 63) / 64, 256, 0, stream>>>(agg1, W2, h2);
    k_gather2<<<(N_NODES + 15) / 16, 256, 0, stream>>>(rowstart, esrc, ecoef, dinv,
                                                       h2, b2, out);
}

// Round 3
// 551.632 us; speedup vs baseline: 7.9431x; 1.1618x over previous
//
#include <hip/hip_runtime.h>

#define N_NODES 100000
#define N_EDGES 1600000
#define IN_DIM 256
#define HIDDEN 128
#define OUT_DIM 64
#define NBLK_SCAN 391  // ceil(100000/256)
#define LDA 40         // LDS leading dim (32 k + 8 pad) for bf16 tiles

typedef __bf16 bf16x8 __attribute__((ext_vector_type(8)));
typedef __bf16 bf16x4 __attribute__((ext_vector_type(4)));
typedef float f32x4 __attribute__((ext_vector_type(4)));

// ---------------------------------------------------------------------------
// degree count (int): deg[dst[e]] += 1   (deg pre-zeroed)
// ---------------------------------------------------------------------------
__global__ void k_deg(const int* __restrict__ dst, int* __restrict__ deg) {
    int e = blockIdx.x * blockDim.x + threadIdx.x;
    if (e < N_EDGES) atomicAdd(&deg[dst[e]], 1);
}

__global__ void k_dinv(const int* __restrict__ deg, float* __restrict__ dinv) {
    int i = blockIdx.x * blockDim.x + threadIdx.x;
    if (i < N_NODES) dinv[i] = rsqrtf((float)deg[i] + 1.0f);
}

// ---------------------------------------------------------------------------
// 3-kernel exclusive scan of deg -> rowstart
// ---------------------------------------------------------------------------
__global__ void k_scan1(const int* __restrict__ deg, int* __restrict__ rowstart,
                        int* __restrict__ bsum) {
    __shared__ int tmp[256];
    int t = threadIdx.x;
    int i = blockIdx.x * 256 + t;
    int v = (i < N_NODES) ? deg[i] : 0;
    tmp[t] = v;
    __syncthreads();
    #pragma unroll
    for (int off = 1; off < 256; off <<= 1) {
        int p = (t >= off) ? tmp[t - off] : 0;
        __syncthreads();
        tmp[t] += p;
        __syncthreads();
    }
    if (i < N_NODES) rowstart[i] = tmp[t] - v;
    if (t == 255) bsum[blockIdx.x] = tmp[255];
}

__global__ void k_scan2(int* __restrict__ bsum, int* __restrict__ rowstart) {
    __shared__ int tmp[512];
    int t = threadIdx.x;
    int v = (t < NBLK_SCAN) ? bsum[t] : 0;
    tmp[t] = v;
    __syncthreads();
    #pragma unroll
    for (int off = 1; off < 512; off <<= 1) {
        int p = (t >= off) ? tmp[t - off] : 0;
        __syncthreads();
        tmp[t] += p;
        __syncthreads();
    }
    if (t < NBLK_SCAN) bsum[t] = tmp[t] - v;
    if (t == 0) rowstart[N_NODES] = N_EDGES;
}

__global__ void k_scan3(int* __restrict__ rowstart, const int* __restrict__ bsum) {
    int i = blockIdx.x * 256 + threadIdx.x;
    if (i < N_NODES) rowstart[i] += bsum[blockIdx.x];
}

// ---------------------------------------------------------------------------
// bucket edges by dst
// ---------------------------------------------------------------------------
__global__ void k_bucket(const int* __restrict__ src, const int* __restrict__ dst,
                         const float* __restrict__ dinv,
                         const int* __restrict__ rowstart, int* __restrict__ cnt,
                         int* __restrict__ esrc, float* __restrict__ ecoef) {
    int e = blockIdx.x * blockDim.x + threadIdx.x;
    if (e >= N_EDGES) return;
    int s = src[e], d = dst[e];
    int p = rowstart[d] + atomicAdd(&cnt[d], 1);
    esrc[p] = s;
    ecoef[p] = dinv[s] * dinv[d];
}

// ---------------------------------------------------------------------------
// GEMM1 (bf16 MFMA): H[M][128] = bf16(X[M][256]) @ bf16(W1[256][128])
// block tile 128x128, 4 waves in 2x2, each wave 64x64 via 4x4 16x16x32 MFMAs
// f32->bf16 conversion fused into LDS staging; H written as bf16.
// ---------------------------------------------------------------------------
__launch_bounds__(256, 2)
__global__ void k_gemm1(const float* __restrict__ X, const float* __restrict__ W1,
                        __bf16* __restrict__ H) {
    __shared__ __attribute__((aligned(16))) __bf16 As[128 * LDA];
    __shared__ __attribute__((aligned(16))) __bf16 Bs[128 * LDA];  // [col][k]

    const int t = threadIdx.x;
    const int wave = t >> 6;
    const int lane = t & 63;
    const int wr = wave >> 1, wc = wave & 1;
    const int lm = lane & 15;
    const int q = lane >> 4;
    const int row0 = blockIdx.x * 128;

    f32x4 acc[4][4] = {};

    for (int k0 = 0; k0 < IN_DIM; k0 += 32) {
        // stage A (128 rows x 32 k), convert f32->bf16
        #pragma unroll
        for (int p = 0; p < 4; ++p) {
            int r = p * 32 + (t >> 3);
            int kk = (t & 7) * 4;
            int g = row0 + r;
            float4 v = make_float4(0.f, 0.f, 0.f, 0.f);
            if (g < N_NODES) v = *(const float4*)&X[g * IN_DIM + k0 + kk];
            __bf16* dp = &As[r * LDA + kk];
            dp[0] = (__bf16)v.x; dp[1] = (__bf16)v.y;
            dp[2] = (__bf16)v.z; dp[3] = (__bf16)v.w;
        }
        // stage B transposed: Bs[col][k]
        #pragma unroll
        for (int p = 0; p < 4; ++p) {
            int idx = p * 256 + t;
            int kk = idx >> 5;
            int c = (idx & 31) * 4;
            float4 v = *(const float4*)&W1[(k0 + kk) * HIDDEN + c];
            Bs[(c + 0) * LDA + kk] = (__bf16)v.x;
            Bs[(c + 1) * LDA + kk] = (__bf16)v.y;
            Bs[(c + 2) * LDA + kk] = (__bf16)v.z;
            Bs[(c + 3) * LDA + kk] = (__bf16)v.w;
        }
        __syncthreads();

        bf16x8 af[4], bfr[4];
        #pragma unroll
        for (int mi = 0; mi < 4; ++mi)
            af[mi] = *(const bf16x8*)&As[(wr * 64 + mi * 16 + lm) * LDA + q * 8];
        #pragma unroll
        for (int ni = 0; ni < 4; ++ni)
            bfr[ni] = *(const bf16x8*)&Bs[(wc * 64 + ni * 16 + lm) * LDA + q * 8];
        #pragma unroll
        for (int mi = 0; mi < 4; ++mi)
            #pragma unroll
            for (int ni = 0; ni < 4; ++ni)
                acc[mi][ni] = __builtin_amdgcn_mfma_f32_16x16x32_bf16(
                    af[mi], bfr[ni], acc[mi][ni], 0, 0, 0);
        __syncthreads();
    }

    // epilogue: C/D layout col=lane&15, row=q*4+reg
    #pragma unroll
    for (int mi = 0; mi < 4; ++mi) {
        #pragma unroll
        for (int r = 0; r < 4; ++r) {
            int grow = row0 + wr * 64 + mi * 16 + q * 4 + r;
            if (grow < N_NODES) {
                #pragma unroll
                for (int ni = 0; ni < 4; ++ni) {
                    int col = wc * 64 + ni * 16 + lm;
                    H[grow * HIDDEN + col] = (__bf16)acc[mi][ni][r];
                }
            }
        }
    }
}

// ---------------------------------------------------------------------------
// gather layer1: AGG[n] = bf16(relu( sum coef*H[src] + dinv^2*H[n] + b1 ))
// 32 lanes per node (128 cols), 8 nodes per block; f32 accumulate
// ---------------------------------------------------------------------------
__launch_bounds__(256)
__global__ void k_gather1(const int* __restrict__ rowstart, const int* __restrict__ esrc,
                          const float* __restrict__ ecoef, const float* __restrict__ dinv,
                          const __bf16* __restrict__ H, const float* __restrict__ b1,
                          __bf16* __restrict__ AGG) {
    int n = blockIdx.x * 8 + (threadIdx.x >> 5);
    if (n >= N_NODES) return;
    int j = (threadIdx.x & 31) * 4;

    float s = dinv[n];
    s = s * s;
    bf16x4 h = *(const bf16x4*)&H[n * HIDDEN + j];
    float acc0 = (float)h[0] * s, acc1 = (float)h[1] * s;
    float acc2 = (float)h[2] * s, acc3 = (float)h[3] * s;

    int p0 = rowstart[n], p1 = rowstart[n + 1];
    for (int p = p0; p < p1; ++p) {
        int sidx = esrc[p];
        float c = ecoef[p];
        bf16x4 v = *(const bf16x4*)&H[sidx * HIDDEN + j];
        acc0 = fmaf((float)v[0], c, acc0);
        acc1 = fmaf((float)v[1], c, acc1);
        acc2 = fmaf((float)v[2], c, acc2);
        acc3 = fmaf((float)v[3], c, acc3);
    }
    float4 bb = *(const float4*)&b1[j];
    bf16x4 o;
    o[0] = (__bf16)fmaxf(acc0 + bb.x, 0.f);
    o[1] = (__bf16)fmaxf(acc1 + bb.y, 0.f);
    o[2] = (__bf16)fmaxf(acc2 + bb.z, 0.f);
    o[3] = (__bf16)fmaxf(acc3 + bb.w, 0.f);
    *(bf16x4*)&AGG[n * HIDDEN + j] = o;
}

// ---------------------------------------------------------------------------
// GEMM2 (bf16 MFMA): H2[M][64] = AGG[M][128] @ bf16(W2[128][64])
// block tile 128x64, 4 waves stacked in m, each 32x64 via 2x4 MFMAs
// ---------------------------------------------------------------------------
__launch_bounds__(256, 2)
__global__ void k_gemm2(const __bf16* __restrict__ AGG, const float* __restrict__ W2,
                        __bf16* __restrict__ H2) {
    __shared__ __attribute__((aligned(16))) __bf16 As[128 * LDA];
    __shared__ __attribute__((aligned(16))) __bf16 Bs[64 * LDA];  // [col][k]

    const int t = threadIdx.x;
    const int wave = t >> 6;
    const int lane = t & 63;
    const int lm = lane & 15;
    const int q = lane >> 4;
    const int row0 = blockIdx.x * 128;

    f32x4 acc[2][4] = {};

    for (int k0 = 0; k0 < HIDDEN; k0 += 32) {
        // stage A (bf16 copy, 16B chunks): 128 rows x 32 k
        #pragma unroll
        for (int p = 0; p < 2; ++p) {
            int idx = p * 256 + t;
            int r = idx >> 2;
            int seg = (idx & 3) * 8;
            int g = row0 + r;
            uint4 v = make_uint4(0u, 0u, 0u, 0u);
            if (g < N_NODES) v = *(const uint4*)&AGG[g * HIDDEN + k0 + seg];
            *(uint4*)&As[r * LDA + seg] = v;
        }
        // stage B transposed: Bs[col][k], f32->bf16
        #pragma unroll
        for (int p = 0; p < 2; ++p) {
            int idx = p * 256 + t;
            int kk = idx >> 4;
            int c = (idx & 15) * 4;
            float4 v = *(const float4*)&W2[(k0 + kk) * OUT_DIM + c];
            Bs[(c + 0) * LDA + kk] = (__bf16)v.x;
            Bs[(c + 1) * LDA + kk] = (__bf16)v.y;
            Bs[(c + 2) * LDA + kk] = (__bf16)v.z;
            Bs[(c + 3) * LDA + kk] = (__bf16)v.w;
        }
        __syncthreads();

        bf16x8 af[2], bfr[4];
        #pragma unroll
        for (int mi = 0; mi < 2; ++mi)
            af[mi] = *(const bf16x8*)&As[(wave * 32 + mi * 16 + lm) * LDA + q * 8];
        #pragma unroll
        for (int ni = 0; ni < 4; ++ni)
            bfr[ni] = *(const bf16x8*)&Bs[(ni * 16 + lm) * LDA + q * 8];
        #pragma unroll
        for (int mi = 0; mi < 2; ++mi)
            #pragma unroll
            for (int ni = 0; ni < 4; ++ni)
                acc[mi][ni] = __builtin_amdgcn_mfma_f32_16x16x32_bf16(
                    af[mi], bfr[ni], acc[mi][ni], 0, 0, 0);
        __syncthreads();
    }

    #pragma unroll
    for (int mi = 0; mi < 2; ++mi) {
        #pragma unroll
        for (int r = 0; r < 4; ++r) {
            int grow = row0 + wave * 32 + mi * 16 + q * 4 + r;
            if (grow < N_NODES) {
                #pragma unroll
                for (int ni = 0; ni < 4; ++ni) {
                    int col = ni * 16 + lm;
                    H2[grow * OUT_DIM + col] = (__bf16)acc[mi][ni][r];
                }
            }
        }
    }
}

// ---------------------------------------------------------------------------
// gather layer2: OUT[n] = relu( sum coef*H2[src] + dinv^2*H2[n] + b2 )  (f32 out)
// 16 lanes per node (64 cols), 16 nodes per block
// ---------------------------------------------------------------------------
__launch_bounds__(256)
__global__ void k_gather2(const int* __restrict__ rowstart, const int* __restrict__ esrc,
                          const float* __restrict__ ecoef, const float* __restrict__ dinv,
                          const __bf16* __restrict__ H2, const float* __restrict__ b2,
                          float* __restrict__ OUT) {
    int n = blockIdx.x * 16 + (threadIdx.x >> 4);
    if (n >= N_NODES) return;
    int j = (threadIdx.x & 15) * 4;

    float s = dinv[n];
    s = s * s;
    bf16x4 h = *(const bf16x4*)&H2[n * OUT_DIM + j];
    float acc0 = (float)h[0] * s, acc1 = (float)h[1] * s;
    float acc2 = (float)h[2] * s, acc3 = (float)h[3] * s;

    int p0 = rowstart[n], p1 = rowstart[n + 1];
    for (int p = p0; p < p1; ++p) {
        int sidx = esrc[p];
        float c = ecoef[p];
        bf16x4 v = *(const bf16x4*)&H2[sidx * OUT_DIM + j];
        acc0 = fmaf((float)v[0], c, acc0);
        acc1 = fmaf((float)v[1], c, acc1);
        acc2 = fmaf((float)v[2], c, acc2);
        acc3 = fmaf((float)v[3], c, acc3);
    }
    float4 bb = *(const float4*)&b2[j];
    float4 o;
    o.x = fmaxf(acc0 + bb.x, 0.f);
    o.y = fmaxf(acc1 + bb.y, 0.f);
    o.z = fmaxf(acc2 + bb.z, 0.f);
    o.w = fmaxf(acc3 + bb.w, 0.f);
    *(float4*)&OUT[n * OUT_DIM + j] = o;
}

extern "C" void kernel_launch(void* const* d_in, const int* in_sizes, int n_in,
                              void* d_out, int out_size, void* d_ws, size_t ws_size,
                              hipStream_t stream) {
    const float* x  = (const float*)d_in[0];
    const int* ei   = (const int*)d_in[1];
    const float* W1 = (const float*)d_in[2];
    const float* b1 = (const float*)d_in[3];
    const float* W2 = (const float*)d_in[4];
    const float* b2 = (const float*)d_in[5];
    float* out = (float*)d_out;

    const int* src = ei;
    const int* dst = ei + N_EDGES;

    char* ws = (char*)d_ws;
    int*    deg      = (int*)   (ws + 0x000000);
    float*  dinv     = (float*) (ws + 0x080000);
    int*    rowstart = (int*)   (ws + 0x100000);
    int*    cnt      = (int*)   (ws + 0x180000);
    int*    bsum     = (int*)   (ws + 0x200000);
    int*    esrc     = (int*)   (ws + 0x280000);   // 6.4 MB
    float*  ecoef    = (float*) (ws + 0x8C0000);   // 6.4 MB
    __bf16* h1       = (__bf16*)(ws + 0x1000000);  // 25.6 MB
    __bf16* agg1     = (__bf16*)(ws + 0x2A00000);  // 25.6 MB
    __bf16* h2       = (__bf16*)(ws + 0x4400000);  // 12.8 MB

    hipMemsetAsync(deg, 0, N_NODES * sizeof(int), stream);
    hipMemsetAsync(cnt, 0, N_NODES * sizeof(int), stream);

    // CSR build
    k_deg<<<(N_EDGES + 255) / 256, 256, 0, stream>>>(dst, deg);
    k_dinv<<<(N_NODES + 255) / 256, 256, 0, stream>>>(deg, dinv);
    k_scan1<<<NBLK_SCAN, 256, 0, stream>>>(deg, rowstart, bsum);
    k_scan2<<<1, 512, 0, stream>>>(bsum, rowstart);
    k_scan3<<<NBLK_SCAN, 256, 0, stream>>>(rowstart, bsum);
    k_bucket<<<(N_EDGES + 255) / 256, 256, 0, stream>>>(src, dst, dinv, rowstart,
                                                        cnt, esrc, ecoef);

    // layer 1
    k_gemm1<<<(N_NODES + 127) / 128, 256, 0, stream>>>(x, W1, h1);
    k_gather1<<<(N_NODES + 7) / 8, 256, 0, stream>>>(rowstart, esrc, ecoef, dinv,
                                                     h1, b1, agg1);
    // layer 2
    k_gemm2<<<(N_NODES + 127) / 128, 256, 0, stream>>>(agg1, W2, h2);
    k_gather2<<<(N_NODES + 15) / 16, 256, 0, stream>>>(rowstart, esrc, ecoef, dinv,
                                                       h2, b2, out);
}